// Round 1
// 247.649 us; speedup vs baseline: 1.0279x; 1.0279x over previous
//
#include <hip/hip_runtime.h>
#include <stdint.h>

// Problem geometry
constexpr int B = 2, X = 256, Y = 256, Z = 64;
constexpr int CO = X * Y * Z;                       // channel stride (elements)
constexpr int YZ = Y * Z;
constexpr long long N_PTS   = (long long)B * X * Y * Z;              // 8388608
constexpr long long M_CELLS = (long long)B * (X-1) * (Y-1) * (Z-1);  // 8193150

constexpr int RPB = 16;                 // y-rows per block
constexpr int XS  = 16;                 // x-columns per block (x-loop length)
constexpr int TPB = 256;                // 4 waves
constexpr int WPB = TPB / 64;
constexpr int BLOCKS = B * (Y / RPB) * (X / XS);   // 2*16*16 = 512 (2 blocks/CU)

// LDS: 3 column buffers; each = 4 ch x (17 rows x 64 z) + pad
constexpr int CHS  = 1152;              // floats per channel slab: 17*64=1088 + 64 pad
constexpr int BUFS = 4 * CHS;           // 4608 floats = 18432 B per column buffer

#define EPSc 1e-10f
#define SIXTH (1.0f / 6.0f)
#define RCPF(v) __builtin_amdgcn_rcpf(v)

// native 4-float vector
typedef float fvec4 __attribute__((ext_vector_type(4)));

#define F4C(v, c) (((c) == 0) ? (v).x : ((c) == 1) ? (v).y : ((c) == 2) ? (v).z : (v).w)

typedef const __attribute__((address_space(1))) uint32_t* gptr_t;
typedef __attribute__((address_space(3))) uint32_t* lptr_t;

__global__ __launch_bounds__(TPB, 2) void loss_main(const float* __restrict__ outs,
                                                    const float* __restrict__ tgts,
                                                    double* __restrict__ partial) {
    // 3 column buffers: 55296 B -> 2 blocks/CU (LDS-limited)
    __shared__ __align__(16) float sm[3 * BUFS];

    const int lane = threadIdx.x & 63;
    const int wv   = threadIdx.x >> 6;
    const int blk  = blockIdx.x;

    // blk = ((b*16 + sy)*16 + xc) : xc fastest (adjacent chunks share one boundary column)
    const int b  = blk >> 8;
    const int r  = blk & 255;
    const int sy = r >> 4;
    const int xc = r & 15;
    const int y0 = sy * RPB;
    const int x0 = xc * XS;

    const float* ob = outs + (size_t)b * 3 * CO;
    const float* tb = tgts + (size_t)b * 4 * CO;

    const int row_l = wv * 4 + (lane >> 4);   // 0..15 (block-local y row)
    const int zi    = (lane & 15) << 2;       // 0,4,...,60
    const int y_own = y0 + row_l;
    const bool yvalid = (y_own < Y - 1);
    const int y16 = (y0 + 16 < Y) ? (y0 + 16) : (Y - 1);

    // this wave's staging channel: wv 0..2 = outputs bx,by,bz ; wv 3 = targets z
    const float* chbase = (wv < 3) ? (ob + (size_t)wv * CO) : (tb + (size_t)3 * CO);

    // per-thread NT base for pointwise targets (ch 0..2)
    const float* tnt = tb + (size_t)y_own * Z + zi;

    // stage one x-column (17 rows x 64 z of this wave's channel) into buf
    auto stage = [&](int xs, float* buf) {
        const float* gbase = chbase + (size_t)xs * YZ;
        float* ldst = buf + wv * CHS;
        const float* gsrc = gbase + (size_t)y0 * Z;     // rows y0..y0+15: 4 KB contiguous
        #pragma unroll
        for (int k = 0; k < 4; ++k) {                   // 4 x (64 lanes x 16 B)
            __builtin_amdgcn_global_load_lds((gptr_t)(gsrc + k * 256 + lane * 4),
                                             (lptr_t)(ldst + k * 256 + lane * 4),
                                             16, 0, 0);
        }
        // halo row 16 (clamped in y): 256 B, width 4
        __builtin_amdgcn_global_load_lds((gptr_t)(gbase + (size_t)y16 * Z + lane),
                                         (lptr_t)(ldst + 16 * 64 + lane),
                                         4, 0, 0);
    };

    float* prv = sm + 2 * BUFS;     // col i-1 (garbage at i=0; never read there)
    float* cur = sm;                // col i
    float* nxt = sm + BUFS;         // col i+1 (staging target)

    // prologue: col x0 + its NT targets
    stage(x0, cur);
    fvec4 tc0, tc1, tc2;
    fvec4 tn0 = {0,0,0,0}, tn1 = {0,0,0,0}, tn2 = {0,0,0,0};
    {
        const float* p = tnt + (size_t)x0 * YZ;
        tc0 = __builtin_nontemporal_load((const fvec4*)(p + 0 * CO));
        tc1 = __builtin_nontemporal_load((const fvec4*)(p + 1 * CO));
        tc2 = __builtin_nontemporal_load((const fvec4*)(p + 2 * CO));
    }
    __syncthreads();   // drains vmcnt: col x0 staged, NT regs ready

    double s_pt = 0.0, s_dv = 0.0;

    #define SMF4(base, ch, row) (*(const fvec4*)((base) + (ch) * CHS + (row) * 64 + zi))

    #pragma unroll 1
    for (int i = 0; i <= XS; ++i) {
        // ---- issue next-column loads FIRST: they overlap this iteration's compute ----
        if (i < XS) {
            int xs1 = x0 + i + 1;
            if (xs1 > X - 1) xs1 = X - 1;               // last chunk: clamp (cells masked)
            stage(xs1, nxt);
            if (i + 1 < XS) {
                const float* p = tnt + (size_t)(x0 + i + 1) * YZ;
                tn0 = __builtin_nontemporal_load((const fvec4*)(p + 0 * CO));
                tn1 = __builtin_nontemporal_load((const fvec4*)(p + 1 * CO));
                tn2 = __builtin_nontemporal_load((const fvec4*)(p + 2 * CO));
            }
        }

        // ---- pointwise losses at column x0+i ----
        if (i < XS) {
            const fvec4 obx = SMF4(cur, 0, row_l);
            const fvec4 oby = SMF4(cur, 1, row_l);
            const fvec4 obz = SMF4(cur, 2, row_l);
            float pt4 = 0.0f;
            #pragma unroll
            for (int c = 0; c < 4; ++c) {
                const float bxp = F4C(obx, c), byp = F4C(oby, c), bzp = F4C(obz, c);
                const float bxt = F4C(tc0, c), byt = F4C(tc1, c), bzt = F4C(tc2, c);
                const float bxt2 = bxt * bxt, byt2 = byt * byt, bzt2 = bzt * bzt;
                const float dxy = bxt2 + byt2;
                const float t1 = bxp * bxp + byp * byp - dxy;
                const float e1 = t1 * t1 * RCPF(dxy + EPSc);
                const float dd = bzp - bzt;
                const float dd2 = dd * dd;
                const float e2 = dd2 * dd2 * RCPF(bzt2 + EPSc);
                const float cr = bxp * byt - byp * bxt;
                const float e3 = cr * cr * RCPF(dxy + bzt2 + EPSc);
                pt4 += e1 + e2 + e3;
            }
            s_pt += (double)pt4;
        }

        // ---- divergence cells between cols x0+i-1 (prv) and x0+i (cur) ----
        if (i >= 1 && (x0 + i - 1) < X - 1) {           // block-uniform
            const fvec4 obx   = SMF4(prv, 0, row_l);
            const fvec4 oby   = SMF4(prv, 1, row_l);
            const fvec4 obz   = SMF4(prv, 2, row_l);
            const fvec4 tzc   = SMF4(prv, 3, row_l);
            const fvec4 obx1  = SMF4(cur, 0, row_l);
            const fvec4 oby1  = SMF4(cur, 1, row_l);
            const fvec4 obz1  = SMF4(cur, 2, row_l);
            const fvec4 tzc1  = SMF4(cur, 3, row_l);
            const fvec4 obxy  = SMF4(prv, 0, row_l + 1);
            const fvec4 obyy  = SMF4(prv, 1, row_l + 1);
            const fvec4 obzy  = SMF4(prv, 2, row_l + 1);
            const fvec4 tzcy  = SMF4(prv, 3, row_l + 1);
            const fvec4 obxy1 = SMF4(cur, 0, row_l + 1);
            const fvec4 obyy1 = SMF4(cur, 1, row_l + 1);
            const fvec4 obzy1 = SMF4(cur, 2, row_l + 1);
            const fvec4 tzcy1 = SMF4(cur, 3, row_l + 1);

            float sxp[5], sxm[5], syp[5], sym[5];
            float zxp[5], zxm[5], zyp[5], zym[5];
            float Sx[5], Sy[5], Sz[5], G2[5];

            #pragma unroll
            for (int t = 0; t < 4; ++t) {
                const float bx00 = F4C(obx, t),   bx10 = F4C(obx1, t);
                const float bx01 = F4C(obxy, t),  bx11 = F4C(obxy1, t);
                const float by00 = F4C(oby, t),   by10 = F4C(oby1, t);
                const float by01 = F4C(obyy, t),  by11 = F4C(obyy1, t);
                const float bz00 = F4C(obz, t),   bz10 = F4C(obz1, t);
                const float bz01 = F4C(obzy, t),  bz11 = F4C(obzy1, t);
                const float zc00 = F4C(tzc, t),   zc10 = F4C(tzc1, t);
                const float zc01 = F4C(tzcy, t),  zc11 = F4C(tzcy1, t);

                sxp[t] = bx10 + bx11;   sxm[t] = bx00 + bx01;
                syp[t] = by01 + by11;   sym[t] = by00 + by10;
                zxp[t] = zc10 + zc11;   zxm[t] = zc00 + zc01;
                zyp[t] = zc01 + zc11;   zym[t] = zc00 + zc10;
                Sx[t] = sxp[t] + sxm[t];
                Sy[t] = syp[t] + sym[t];
                Sz[t] = (bz00 + bz01) + (bz10 + bz11);
                G2[t] = 0.025f * Sz[t]
                      + SIXTH * ((bx00 + sxp[t]) * (zc00 - zc10)
                               + (bx01 + sxp[t]) * (zc01 - zc11)
                               + (by10 + syp[t]) * (zc10 - zc11)
                               + (by00 + syp[t]) * (zc00 - zc01));
            }
            // level 4 = lane+1's level 0 (z is the lane-contiguous dim)
            sxp[4] = __shfl_down(sxp[0], 1);
            sxm[4] = __shfl_down(sxm[0], 1);
            syp[4] = __shfl_down(syp[0], 1);
            sym[4] = __shfl_down(sym[0], 1);
            zxp[4] = __shfl_down(zxp[0], 1);
            zxm[4] = __shfl_down(zxm[0], 1);
            zyp[4] = __shfl_down(zyp[0], 1);
            zym[4] = __shfl_down(zym[0], 1);
            Sz[4]  = __shfl_down(Sz[0],  1);
            G2[4]  = __shfl_down(G2[0],  1);
            Sx[4] = sxp[4] + sxm[4];
            Sy[4] = syp[4] + sym[4];

            float dv4 = 0.0f;
            #pragma unroll
            for (int c = 0; c < 4; ++c) {
                const float fx = (sxp[c] + sxp[c+1]) * (zxp[c+1] - zxp[c])
                               - (sxm[c] + sxm[c+1]) * (zxm[c+1] - zxm[c])
                               + (syp[c] + syp[c+1]) * (zyp[c+1] - zyp[c])
                               - (sym[c] + sym[c+1]) * (zym[c+1] - zym[c]);
                const float num2 = 0.125f * fx + (G2[c+1] - G2[c]);
                const float SxS = Sx[c] + Sx[c+1];
                const float SyS = Sy[c] + Sy[c+1];
                const float SzS = Sz[c] + Sz[c+1];
                const float q = SxS * SxS + SyS * SyS + SzS * SzS;
                const float den = 0.015625f * q + EPSc;
                const float v = num2 * num2 * RCPF(den);
                const bool ok = yvalid && ((zi + c) < Z - 1);
                dv4 += ok ? v : 0.0f;
            }
            s_dv += (double)dv4;
        }

        // drain staging (vmcnt) + protect prv before it becomes next stage target
        if (i < XS) __syncthreads();

        float* tmp = prv; prv = cur; cur = nxt; nxt = tmp;
        tc0 = tn0; tc1 = tn1; tc2 = tn2;
    }

    // wave reduction (64 lanes)
    for (int off = 32; off > 0; off >>= 1) {
        s_pt += __shfl_down(s_pt, off);
        s_dv += __shfl_down(s_dv, off);
    }

    __shared__ double lds_pt[WPB];
    __shared__ double lds_dv[WPB];
    if (lane == 0) { lds_pt[wv] = s_pt; lds_dv[wv] = s_dv; }
    __syncthreads();
    if (threadIdx.x == 0) {
        double p = 0.0, d = 0.0;
        #pragma unroll
        for (int w = 0; w < WPB; ++w) { p += lds_pt[w]; d += lds_dv[w]; }
        partial[2 * blockIdx.x]     = p;
        partial[2 * blockIdx.x + 1] = d;
    }
}

__global__ __launch_bounds__(256) void loss_finalize(const double* __restrict__ partial,
                                                     float* __restrict__ out) {
    double s0 = 0.0, s1 = 0.0;
    for (int i = threadIdx.x; i < BLOCKS; i += 256) {
        s0 += partial[2 * i];
        s1 += partial[2 * i + 1];
    }
    const int lane = threadIdx.x & 63;
    const int wave = threadIdx.x >> 6;
    for (int off = 32; off > 0; off >>= 1) {
        s0 += __shfl_down(s0, off);
        s1 += __shfl_down(s1, off);
    }
    __shared__ double l0[4], l1[4];
    if (lane == 0) { l0[wave] = s0; l1[wave] = s1; }
    __syncthreads();
    if (threadIdx.x == 0) {
        double p = 0.0, d = 0.0;
        #pragma unroll
        for (int w = 0; w < 4; ++w) { p += l0[w]; d += l1[w]; }
        // out0 = W_B*loss_b + W_PARALLEL*loss_parallel = 1000 * sum_pt / N
        const double out0 = 1000.0 * (p / (double)N_PTS);
        // s_dv accumulates v = num2^2/den with num = 0.1*num2:
        //   out1 = 100 * (0.01 * sum_v / M) / 1e-4 = 1e4 * sum_v / M
        const double out1 = 10000.0 * (d / (double)M_CELLS);
        out[0] = (float)out0;
        out[1] = (float)out1;
    }
}

extern "C" void kernel_launch(void* const* d_in, const int* in_sizes, int n_in,
                              void* d_out, int out_size, void* d_ws, size_t ws_size,
                              hipStream_t stream) {
    const float* outs = (const float*)d_in[0];   // (2,3,256,256,64) f32
    const float* tgts = (const float*)d_in[1];   // (2,4,256,256,64) f32
    float* out = (float*)d_out;                  // 2 scalars f32
    double* partial = (double*)d_ws;             // BLOCKS*2 doubles = 8 KB

    loss_main<<<BLOCKS, TPB, 0, stream>>>(outs, tgts, partial);
    loss_finalize<<<1, 256, 0, stream>>>(partial, out);
}